// Round 5
// baseline (261.510 us; speedup 1.0000x reference)
//
#include <hip/hip_runtime.h>
#include <stdint.h>
#include <math.h>

// Problem constants
constexpr int T_ = 4;
constexpr int B_ = 8;
constexpr int C_ = 256;
constexpr int N_ = 256;          // H*W
constexpr int TN_ = 1024;        // T*N
constexpr int NH_ = 8;           // heads
constexpr int O3_ = 768;         // 3*C
constexpr int BIAS_ROWS_ = 6727; // 7*31*31
constexpr int BCOL_P_ = 6784;    // padded per-head bias column

__device__ __constant__ int TI_OF[10] = {0,1,1,2,2,2,3,3,3,3};
__device__ __constant__ int TJ_OF[10] = {0,0,1,0,1,2,0,1,2,3};

__device__ __forceinline__ float quant1f(float m) {
    return rintf(fminf(fmaxf(m, 0.0f), 1.0f));
}

// ---------------------------------------------------------------------------
// K0: compact bias_table column per head: bcol[h][r] = bias_table[r*8+h]
// ---------------------------------------------------------------------------
__global__ __launch_bounds__(256) void k0_bcol(
    const float* __restrict__ bias_table, float* __restrict__ bcol)
{
    const int idx = blockIdx.x * 256 + threadIdx.x;
    if (idx >= NH_ * BCOL_P_) return;
    const int h = idx / BCOL_P_, r = idx % BCOL_P_;
    bcol[idx] = (r < BIAS_ROWS_) ? bias_table[(size_t)r * NH_ + h] : 0.0f;
}

// ---------------------------------------------------------------------------
// K1: qkv = BN(w_qkv @ xf)   out[b][o][l]
// 96x128 tile, 12x4 microtile, K-chunk 16, double-buffered LDS: one barrier
// per chunk, next chunk's global loads in flight during compute.
// Ascending-k accumulation (bit-identical to prior rounds).
// ---------------------------------------------------------------------------
__global__ __launch_bounds__(256) void k1_qkv_gemm(
    const float* __restrict__ x, const float* __restrict__ w,
    const float* __restrict__ gamma, const float* __restrict__ beta,
    const float* __restrict__ mean, const float* __restrict__ var,
    float* __restrict__ out)
{
    __shared__ float At[2][16][100];  // [buf][k][m]
    __shared__ float Bt[2][16][132];  // [buf][k][n]
    const int b = blockIdx.z;
    const int oBase = blockIdx.y * 96;
    const int lBase = blockIdx.x * 128;
    const int tid = threadIdx.x;
    const int tx = tid & 31;
    const int ty = tid >> 5;
    const float* xb = x + (size_t)b * C_ * TN_;

    float acc[12][4];
#pragma unroll
    for (int i = 0; i < 12; ++i)
#pragma unroll
        for (int j = 0; j < 4; ++j) acc[i][j] = 0.0f;

    const int b_kk = tid >> 4, b_c4 = (tid & 15) * 4;
    // A loader indices
    int a_row[3], a_k2[3];
#pragma unroll
    for (int r = 0; r < 3; ++r) {
        const int q = tid + 256 * r;
        a_row[r] = q >> 3;
        a_k2[r] = (q & 7) * 2;
    }

    float2 aReg[3];
    float4 bReg[2];

    // prologue: load chunk 0
#pragma unroll
    for (int r = 0; r < 3; ++r)
        aReg[r] = *(const float2*)&w[(size_t)(oBase + a_row[r]) * C_ + a_k2[r]];
#pragma unroll
    for (int r = 0; r < 2; ++r)
        bReg[r] = *(const float4*)&xb[(size_t)b_kk * TN_ + lBase + b_c4 + 64 * r];
#pragma unroll
    for (int r = 0; r < 3; ++r) {
        At[0][a_k2[r]][a_row[r]] = aReg[r].x;
        At[0][a_k2[r] + 1][a_row[r]] = aReg[r].y;
    }
#pragma unroll
    for (int r = 0; r < 2; ++r)
        *(float4*)&Bt[0][b_kk][b_c4 + 64 * r] = bReg[r];
    __syncthreads();

    for (int kc = 0; kc < 16; ++kc) {
        const int buf = kc & 1;
        if (kc < 15) {
            const int k0 = (kc + 1) * 16;
#pragma unroll
            for (int r = 0; r < 3; ++r)
                aReg[r] = *(const float2*)&w[(size_t)(oBase + a_row[r]) * C_ + k0 + a_k2[r]];
#pragma unroll
            for (int r = 0; r < 2; ++r)
                bReg[r] = *(const float4*)&xb[(size_t)(k0 + b_kk) * TN_ + lBase + b_c4 + 64 * r];
        }
#pragma unroll
        for (int cc = 0; cc < 16; ++cc) {
            float a[12], bb[4];
            *(float4*)&a[0] = *(const float4*)&At[buf][cc][ty * 4];
            *(float4*)&a[4] = *(const float4*)&At[buf][cc][32 + ty * 4];
            *(float4*)&a[8] = *(const float4*)&At[buf][cc][64 + ty * 4];
            *(float4*)&bb[0] = *(const float4*)&Bt[buf][cc][tx * 4];
#pragma unroll
            for (int i = 0; i < 12; ++i)
#pragma unroll
                for (int j = 0; j < 4; ++j) acc[i][j] += a[i] * bb[j];
        }
        if (kc < 15) {
            const int nb = buf ^ 1;
#pragma unroll
            for (int r = 0; r < 3; ++r) {
                At[nb][a_k2[r]][a_row[r]] = aReg[r].x;
                At[nb][a_k2[r] + 1][a_row[r]] = aReg[r].y;
            }
#pragma unroll
            for (int r = 0; r < 2; ++r)
                *(float4*)&Bt[nb][b_kk][b_c4 + 64 * r] = bReg[r];
            __syncthreads();
        }
    }

#pragma unroll
    for (int i = 0; i < 12; ++i) {
        const int o = oBase + (i >> 2) * 32 + ty * 4 + (i & 3);
        const float inv = 1.0f / sqrtf(var[o] + 1e-5f);
        const float g = gamma[o] * inv;
        const float mn = mean[o], bt = beta[o];
        float4 st;
        st.x = (acc[i][0] - mn) * g + bt;
        st.y = (acc[i][1] - mn) * g + bt;
        st.z = (acc[i][2] - mn) * g + bt;
        st.w = (acc[i][3] - mn) * g + bt;
        *(float4*)&out[((size_t)b * O3_ + o) * TN_ + lBase + tx * 4] = st;
    }
}

// ---------------------------------------------------------------------------
// K2: LIF over t on qkv_bn, pack 32 head-dims into one uint32 spike word.
// ---------------------------------------------------------------------------
__global__ __launch_bounds__(256) void k2_lif_pack(
    const float* __restrict__ qkv,
    uint32_t* __restrict__ qb, uint32_t* __restrict__ kb, uint32_t* __restrict__ vb)
{
    const int n = threadIdx.x;
    const int g = blockIdx.x;
    const int b = blockIdx.y;
    const int which = g >> 3, h = g & 7;
    uint32_t* dst = (which == 0) ? qb : (which == 1) ? kb : vb;
    const float* src = qkv + ((size_t)b * O3_ + g * 32) * TN_;

    float memv[32];
#pragma unroll
    for (int d = 0; d < 32; ++d) memv[d] = 0.0f;
    uint32_t prev = 0;

    for (int t = 0; t < T_; ++t) {
        uint32_t bits = 0;
#pragma unroll
        for (int d = 0; d < 32; ++d) {
            const float xv = src[(size_t)d * TN_ + t * N_ + n];
            const float m = (memv[d] - 0.5f * (float)((prev >> d) & 1u)) * 0.25f + xv;
            memv[d] = m;
            const float s = quant1f(m);
            bits |= ((uint32_t)s) << d;
        }
        prev = bits;
        dst[((size_t)b * NH_ + h) * TN_ + t * N_ + n] = bits;
    }
}

// ---------------------------------------------------------------------------
// K3t: ballot bit-transpose of k and v spikes into per-(b,h,t) column masks.
// ---------------------------------------------------------------------------
__global__ __launch_bounds__(256) void k3_transpose(
    const uint32_t* __restrict__ kb, const uint32_t* __restrict__ vb,
    uint64_t* __restrict__ ksel, uint64_t* __restrict__ vsel)
{
    const int t = blockIdx.x;
    const int h = blockIdx.y;
    const int b = blockIdx.z;
    const int bh = b * NH_ + h;
    const int tid = threadIdx.x;
    const int q = tid >> 6, lane = tid & 63;
    const int j = t * N_ + q * 64 + lane;

    const uint32_t kw = kb[(size_t)bh * TN_ + j];
    const uint32_t vw = vb[(size_t)bh * TN_ + j];
#pragma unroll
    for (int d = 0; d < 32; ++d) {
        const uint64_t mk = __ballot((kw >> d) & 1u);
        const uint64_t mv = __ballot((vw >> d) & 1u);
        if (lane == 0) {
            ksel[((size_t)(bh * 4 + t) * 32 + d) * 4 + q] = mk;
            vsel[((size_t)(bh * 4 + t) * 32 + d) * 4 + q] = mv;
        }
    }
}

// ---------------------------------------------------------------------------
// K3g: G_t[d2][d] = sum_{j < (t+1)*256} k[j,d2]*v[j,d]  (cumulative over t)
// ---------------------------------------------------------------------------
__global__ __launch_bounds__(256) void k3_gram(
    const uint64_t* __restrict__ ksel, const uint64_t* __restrict__ vsel,
    float* __restrict__ Gf)
{
    const int bh = blockIdx.x;
    const int tid = threadIdx.x;
    const int d = tid & 31;
#pragma unroll
    for (int s = 0; s < 4; ++s) {
        const int d2 = (tid >> 5) + 8 * s;
        int cum = 0;
#pragma unroll
        for (int t = 0; t < T_; ++t) {
            const uint64_t* kp = ksel + ((size_t)(bh * 4 + t) * 32 + d2) * 4;
            const uint64_t* vp = vsel + ((size_t)(bh * 4 + t) * 32 + d) * 4;
            int p = 0;
#pragma unroll
            for (int w = 0; w < 4; ++w) p += __popcll(kp[w] & vp[w]);
            cum += p;
            Gf[(size_t)(bh * 4 + t) * 1024 + d2 * 32 + d] = (float)cum;
        }
    }
}

// ---------------------------------------------------------------------------
// K3s1 v2: S1[i,d] = sum_{d2} qbit[i,d2] * G_ti[d2,d] -> oatt (unscaled)
// G column held in 32 registers; no LDS in inner loop. 1024 blocks.
// Block: (grp, h, b); grp encodes ti (grp>>2) and 64-i segment (grp&3).
// ---------------------------------------------------------------------------
__global__ __launch_bounds__(256) void k3_s1(
    const uint32_t* __restrict__ qb, const float* __restrict__ Gf,
    float* __restrict__ oatt)
{
    const int grp = blockIdx.x;          // 0..15
    const int ti = grp >> 2, seg = grp & 3;
    const int h = blockIdx.y;
    const int b = blockIdx.z;
    const int bh = b * NH_ + h;
    const int tid = threadIdx.x;
    const int d = tid & 31;
    const int ig = tid >> 5;             // 0..7: 8 i's each

    const float* gsrc = Gf + (size_t)(bh * 4 + ti) * 1024 + d;
    float g[32];
#pragma unroll
    for (int d2 = 0; d2 < 32; ++d2) g[d2] = gsrc[d2 * 32];

    const uint32_t* qbh = qb + (size_t)bh * TN_;
    const int i0 = ti * N_ + seg * 64 + ig * 8;
#pragma unroll
    for (int s = 0; s < 8; ++s) {
        const int i = i0 + s;
        const uint32_t q = qbh[i];
        float acc = 0.0f;
#pragma unroll
        for (int d2 = 0; d2 < 32; ++d2)
            acc += ((q >> d2) & 1u) ? g[d2] : 0.0f;
        oatt[((size_t)b * TN_ + i) * C_ + h * 32 + d] = acc;
    }
}

// ---------------------------------------------------------------------------
// K3gemm v3: balanced split-K bias GEMM.
// Block = (nT(128 cols), iT(64 rows), h*10+pair); K = 256 (one tj), 640 blocks.
// A-tile staged per-chunk into LDS transposed+shifted -> aligned b128 reads.
// 4x8 microtile: 32 FMA per (1 A-b128 + 2 B-b128).
// ---------------------------------------------------------------------------
__global__ __launch_bounds__(256) void k3_bias_gemm(
    const uint32_t* __restrict__ vb, const float* __restrict__ bcol,
    float* __restrict__ p0, float* __restrict__ p1,
    float* __restrict__ p2, float* __restrict__ p3)
{
    __shared__ float sbl[640];
    __shared__ float At[16][68];   // [j-in-chunk][i-local]
    __shared__ float Bt[16][132];  // [j-in-chunk][n-local]

    const int z = blockIdx.z;            // 0..79
    const int h = z / 10;
    const int p = z % 10;
    const int ti = TI_OF[p], tj = TJ_OF[p];
    const int dt = ti - tj;
    const int iT = blockIdx.y;           // 0..3
    const int nBase = blockIdx.x * 128;  // 0 or 128
    const int tid = threadIdx.x;

    // stage bias window (indices used fall in [0,589) of this window)
    const int base = 3363 + 961 * dt + 124 * iT - 480;
    const float* bch = bcol + h * BCOL_P_;
    for (int s = tid; s < 640; s += 256) sbl[s] = bch[base + s];

    const int ty = tid >> 4, tx = tid & 15;

    // A-staging indices: thread (ccS = tx, iBase4 = ty*4)
    const int ccS = tx;
    const int iBase4 = ty * 4;
    const int sIdxBase = 31 * (iBase4 >> 4) + (iBase4 & 15) + 480 - ccS;

    // B-staging indices: thread (kkS = ty, n8 = tx*8)
    const int kkS = ty;
    const int n8 = tx * 8;
    const int nS = nBase + n8;
    const int bS = nS >> 5, d0S = nS & 31;
    const uint32_t* vbw = vb + ((size_t)bS * NH_ + h) * TN_ + tj * 256 + kkS;

    float acc[4][8];
#pragma unroll
    for (int i = 0; i < 4; ++i)
#pragma unroll
        for (int j = 0; j < 8; ++j) acc[i][j] = 0.0f;

    __syncthreads();  // sbl ready

    for (int kc = 0; kc < 16; ++kc) {
        // stage A: At[cc][iLoc] = bias value for (row iLoc, j = kc*16+cc)
        {
            const int s0 = sIdxBase - 31 * kc;
            float4 av;
            av.x = sbl[s0];
            av.y = sbl[s0 + 1];
            av.z = sbl[s0 + 2];
            av.w = sbl[s0 + 3];
            *(float4*)&At[ccS][iBase4] = av;
        }
        // stage B: expand v bits for j = tj*256 + kc*16 + kkS, cols nS..nS+7
        {
            const uint32_t wd = vbw[kc * 16];
            float4 b0, b1;
            b0.x = (float)((wd >> d0S) & 1u);
            b0.y = (float)((wd >> (d0S + 1)) & 1u);
            b0.z = (float)((wd >> (d0S + 2)) & 1u);
            b0.w = (float)((wd >> (d0S + 3)) & 1u);
            b1.x = (float)((wd >> (d0S + 4)) & 1u);
            b1.y = (float)((wd >> (d0S + 5)) & 1u);
            b1.z = (float)((wd >> (d0S + 6)) & 1u);
            b1.w = (float)((wd >> (d0S + 7)) & 1u);
            *(float4*)&Bt[kkS][n8] = b0;
            *(float4*)&Bt[kkS][n8 + 4] = b1;
        }
        __syncthreads();
#pragma unroll
        for (int cc = 0; cc < 16; ++cc) {
            float a[4], bb[8];
            *(float4*)&a[0] = *(const float4*)&At[cc][ty * 4];
            *(float4*)&bb[0] = *(const float4*)&Bt[cc][tx * 8];
            *(float4*)&bb[4] = *(const float4*)&Bt[cc][tx * 8 + 4];
#pragma unroll
            for (int i = 0; i < 4; ++i)
#pragma unroll
                for (int j = 0; j < 8; ++j) acc[i][j] += a[i] * bb[j];
        }
        __syncthreads();
    }

    // store to partial plane tj, packed rows, layout [b][rowL][c]
    float* plane = (tj == 0) ? p0 : (tj == 1) ? p1 : (tj == 2) ? p2 : p3;
    const int nrows = (4 - tj) * 256;
    const int c0 = h * 32 + d0S;
#pragma unroll
    for (int r = 0; r < 4; ++r) {
        const int rowL = dt * 256 + iT * 64 + ty * 4 + r;
        float* dst = &plane[((size_t)bS * nrows + rowL) * 256 + c0];
        float4 s0, s1;
        s0.x = acc[r][0]; s0.y = acc[r][1]; s0.z = acc[r][2]; s0.w = acc[r][3];
        s1.x = acc[r][4]; s1.y = acc[r][5]; s1.z = acc[r][6]; s1.w = acc[r][7];
        *(float4*)&dst[0] = s0;
        *(float4*)&dst[4] = s1;
    }
}

// ---------------------------------------------------------------------------
// K4: combine S1 + bias partials, scale 0.125, LIF over t -> bit-packed spikes
// ---------------------------------------------------------------------------
__global__ __launch_bounds__(256) void k4_lif2(
    const float* __restrict__ oatt,
    const float* __restrict__ p0, const float* __restrict__ p1,
    const float* __restrict__ p2, const float* __restrict__ p3,
    uint32_t* __restrict__ s2c)
{
    const int c = threadIdx.x;
    const int n = blockIdx.x;
    const int b = blockIdx.y;
    const int lane = c & 63;
    float memv = 0.0f, spk = 0.0f;
    for (int t = 0; t < T_; ++t) {
        const int l = t * N_ + n;
        float v = oatt[((size_t)b * TN_ + l) * C_ + c];
        v += p0[((size_t)b * 1024 + l) * 256 + c];
        if (t >= 1) v += p1[((size_t)b * 768 + (l - 256)) * 256 + c];
        if (t >= 2) v += p2[((size_t)b * 512 + (l - 512)) * 256 + c];
        if (t >= 3) v += p3[((size_t)b * 256 + (l - 768)) * 256 + c];
        const float m = (memv - 0.5f * spk) * 0.25f + 0.125f * v;
        memv = m;
        const float s = quant1f(m);
        spk = s;
        const uint64_t mask = __ballot(s != 0.0f);
        if (lane == 0)
            s2c[((size_t)b * TN_ + l) * 8 + (c >> 5)] = (uint32_t)mask;
        else if (lane == 32)
            s2c[((size_t)b * TN_ + l) * 8 + (c >> 5)] = (uint32_t)(mask >> 32);
    }
}

// ---------------------------------------------------------------------------
// K5: proj GEMM + bias + BN, B operand expanded from bit-packed spikes.
// ---------------------------------------------------------------------------
__global__ __launch_bounds__(256) void k5_proj_gemm(
    const uint32_t* __restrict__ s2c, const float* __restrict__ w,
    const float* __restrict__ bp,
    const float* __restrict__ gamma, const float* __restrict__ beta,
    const float* __restrict__ mean, const float* __restrict__ var,
    float* __restrict__ pbn)
{
    __shared__ float At[16][36];
    __shared__ float Bt[16][132];
    const int b = blockIdx.z;
    const int oBase = blockIdx.y * 32;
    const int lBase = blockIdx.x * 128;
    const int tid = threadIdx.x;
    const int tx = tid & 31;
    const int ty = tid >> 5;

    const int a_row = tid >> 3, a_k2 = (tid & 7) * 2;
    const int b_ll = tid >> 1, b_sub = tid & 1;
    const uint32_t* srow = s2c + ((size_t)b * TN_ + lBase + b_ll) * 8;

    float acc[4][4];
#pragma unroll
    for (int i = 0; i < 4; ++i)
#pragma unroll
        for (int j = 0; j < 4; ++j) acc[i][j] = 0.0f;

    for (int kc = 0; kc < 16; ++kc) {
        const int k0 = kc * 16;
        {
            const float2 v = *(const float2*)&w[(size_t)(oBase + a_row) * C_ + k0 + a_k2];
            At[a_k2][a_row] = v.x;
            At[a_k2 + 1][a_row] = v.y;
        }
        {
            const uint32_t wd = srow[kc >> 1];
            const int sh = ((kc & 1) << 4) + (b_sub << 3);
#pragma unroll
            for (int u = 0; u < 8; ++u)
                Bt[(b_sub << 3) + u][b_ll] = (float)((wd >> (sh + u)) & 1u);
        }
        __syncthreads();
#pragma unroll
        for (int cc = 0; cc < 16; ++cc) {
            float a[4], bb[4];
            *(float4*)&a[0] = *(const float4*)&At[cc][ty * 4];
            *(float4*)&bb[0] = *(const float4*)&Bt[cc][tx * 4];
#pragma unroll
            for (int i = 0; i < 4; ++i)
#pragma unroll
                for (int j = 0; j < 4; ++j) acc[i][j] += a[i] * bb[j];
        }
        __syncthreads();
    }

#pragma unroll
    for (int i = 0; i < 4; ++i) {
        const int o = oBase + ty * 4 + i;
        const float inv = 1.0f / sqrtf(var[o] + 1e-5f);
        const float g = gamma[o] * inv;
        const float mn = mean[o], bt = beta[o], bpo = bp[o];
        float4 st;
        st.x = ((acc[i][0] + bpo) - mn) * g + bt;
        st.y = ((acc[i][1] + bpo) - mn) * g + bt;
        st.z = ((acc[i][2] + bpo) - mn) * g + bt;
        st.w = ((acc[i][3] + bpo) - mn) * g + bt;
        *(float4*)&pbn[((size_t)b * C_ + o) * TN_ + lBase + tx * 4] = st;
    }
}

// ---------------------------------------------------------------------------
// K6: final LIF over t, write output [T][B][C][N]
// ---------------------------------------------------------------------------
__global__ __launch_bounds__(256) void k6_lif3(
    const float* __restrict__ pbn, float* __restrict__ out)
{
    const int n = threadIdx.x;
    const int c = blockIdx.x;
    const int b = blockIdx.y;
    const float* src = pbn + ((size_t)b * C_ + c) * TN_;
    float memv = 0.0f, spk = 0.0f;
    for (int t = 0; t < T_; ++t) {
        const float m = (memv - 0.5f * spk) * 0.25f + src[t * N_ + n];
        memv = m;
        const float s = quant1f(m);
        out[(((size_t)t * B_ + b) * C_ + c) * N_ + n] = s;
        spk = s;
    }
}

// ---------------------------------------------------------------------------
extern "C" void kernel_launch(void* const* d_in, const int* in_sizes, int n_in,
                              void* d_out, int out_size, void* d_ws, size_t ws_size,
                              hipStream_t stream)
{
    const float* x          = (const float*)d_in[0];
    const float* w_qkv      = (const float*)d_in[1];
    const float* qkv_gamma  = (const float*)d_in[2];
    const float* qkv_beta   = (const float*)d_in[3];
    const float* qkv_mean   = (const float*)d_in[4];
    const float* qkv_var    = (const float*)d_in[5];
    const float* bias_table = (const float*)d_in[6];
    const float* w_proj     = (const float*)d_in[7];
    const float* b_proj     = (const float*)d_in[8];
    const float* proj_gamma = (const float*)d_in[9];
    const float* proj_beta  = (const float*)d_in[10];
    const float* proj_mean  = (const float*)d_in[11];
    const float* proj_var   = (const float*)d_in[12];
    float* out = (float*)d_out;

    // workspace layout (bytes); identical to R4
    char* ws = (char*)d_ws;
    float*    qkv_bn = (float*)(ws + 0);            // 25165824 B (dead after K2)
    uint64_t* ksel   = (uint64_t*)(ws + 0);         //   262144 B (after K2)
    uint64_t* vsel   = (uint64_t*)(ws + 262144);    //   262144 B
    float*    Gf     = (float*)(ws + 524288);       //  1048576 B (tail overlaps
                                                    //  part0 -- safe: Gf reads
                                                    //  complete before part0 writes)
    float*    part0  = (float*)(ws + 1048576);      //  8388608 B
    float*    part1  = (float*)(ws + 9437184);      //  6291456 B
    float*    part2  = (float*)(ws + 15728640);     //  4194304 B
    float*    part3  = (float*)(ws + 19922944);     //  2097152 B
    float*    oatt   = (float*)(ws + 25165824);     //  8388608 B (S1, unscaled)
    uint32_t* s2c    = (uint32_t*)(ws + 33554432);  //   262144 B (packed spikes)
    float*    pbn    = (float*)(ws + 41943040);     //  8388608 B
    uint32_t* qbits  = (uint32_t*)(ws + 50331648);  //   262144 B
    uint32_t* kbits  = (uint32_t*)(ws + 50593792);
    uint32_t* vbits  = (uint32_t*)(ws + 50855936);
    float*    bcol   = (float*)(ws + 51118080);     //   217088 B, end 51335168

    k0_bcol<<<dim3((NH_ * BCOL_P_ + 255) / 256), 256, 0, stream>>>(bias_table, bcol);

    k1_qkv_gemm<<<dim3(8, 8, 8), 256, 0, stream>>>(
        x, w_qkv, qkv_gamma, qkv_beta, qkv_mean, qkv_var, qkv_bn);

    k2_lif_pack<<<dim3(24, 8), 256, 0, stream>>>(qkv_bn, qbits, kbits, vbits);

    k3_transpose<<<dim3(4, 8, 8), 256, 0, stream>>>(kbits, vbits, ksel, vsel);

    k3_gram<<<dim3(64), 256, 0, stream>>>(ksel, vsel, Gf);

    k3_s1<<<dim3(16, 8, 8), 256, 0, stream>>>(qbits, Gf, oatt);

    k3_bias_gemm<<<dim3(2, 4, 80), 256, 0, stream>>>(
        vbits, bcol, part0, part1, part2, part3);

    k4_lif2<<<dim3(256, 8), 256, 0, stream>>>(oatt, part0, part1, part2, part3, s2c);

    k5_proj_gemm<<<dim3(8, 8, 8), 256, 0, stream>>>(
        s2c, w_proj, b_proj, proj_gamma, proj_beta, proj_mean, proj_var, pbn);

    k6_lif3<<<dim3(256, 8), 256, 0, stream>>>(pbn, out);
}

// Round 6
// 229.754 us; speedup vs baseline: 1.1382x; 1.1382x over previous
//
#include <hip/hip_runtime.h>
#include <stdint.h>
#include <math.h>

// Problem constants
constexpr int T_ = 4;
constexpr int B_ = 8;
constexpr int C_ = 256;
constexpr int N_ = 256;          // H*W
constexpr int TN_ = 1024;        // T*N
constexpr int NH_ = 8;           // heads
constexpr int O3_ = 768;         // 3*C
constexpr int BIAS_ROWS_ = 6727; // 7*31*31

__device__ __constant__ int TI_OF[10] = {0,1,1,2,2,2,3,3,3,3};
__device__ __constant__ int TJ_OF[10] = {0,0,1,0,1,2,0,1,2,3};

__device__ __forceinline__ float quant1f(float m) {
    return rintf(fminf(fmaxf(m, 0.0f), 1.0f));
}

// ---------------------------------------------------------------------------
// K1: qkv = BN(w_qkv @ xf)   out[b][o][l]
// 64(M=o) x 128(N=l) tile, 256 threads, 8x4 microtile, K-chunk 16.
// Single-buffer (R5's explicit dbuf regressed: VGPR 172, occ 10%).
// Grid 8x12x8 = 768 blocks = 3/CU for barrier-stall hiding.
// Ascending-k accumulation (bit-identical to prior rounds).
// ---------------------------------------------------------------------------
__global__ __launch_bounds__(256) void k1_qkv_gemm(
    const float* __restrict__ x, const float* __restrict__ w,
    const float* __restrict__ gamma, const float* __restrict__ beta,
    const float* __restrict__ mean, const float* __restrict__ var,
    float* __restrict__ out)
{
    __shared__ float At[16][68];   // [k][m], m=64 (+4 pad)
    __shared__ float Bt[16][132];  // [k][n], n=128 (+4 pad)
    const int b = blockIdx.z;
    const int oBase = blockIdx.y * 64;
    const int lBase = blockIdx.x * 128;
    const int tid = threadIdx.x;
    const int tx = tid & 31;        // n: cols tx*4..+3
    const int ty = tid >> 5;        // m: rows {0,32}+ty*4..+3
    const float* xb = x + (size_t)b * C_ * TN_;

    float acc[8][4];
#pragma unroll
    for (int i = 0; i < 8; ++i)
#pragma unroll
        for (int j = 0; j < 4; ++j) acc[i][j] = 0.0f;

    const int b_kk = tid >> 4, b_c4 = (tid & 15) * 4;
    const int a_row = tid >> 3, a_k2 = (tid & 7) * 2;

    for (int kc = 0; kc < 16; ++kc) {
        const int k0 = kc * 16;
        // A: 64 rows x 16 k, 1024 floats as 512 float2, store transposed
#pragma unroll
        for (int r = 0; r < 2; ++r) {
            const int row = a_row + 32 * r;
            const float2 v = *(const float2*)&w[(size_t)(oBase + row) * C_ + k0 + a_k2];
            At[a_k2][row] = v.x;
            At[a_k2 + 1][row] = v.y;
        }
        // B: 16 k x 128 l, float4 coalesced
#pragma unroll
        for (int r = 0; r < 2; ++r) {
            const float4 v = *(const float4*)&xb[(size_t)(k0 + b_kk) * TN_ + lBase + b_c4 + 64 * r];
            *(float4*)&Bt[b_kk][b_c4 + 64 * r] = v;
        }
        __syncthreads();
#pragma unroll
        for (int cc = 0; cc < 16; ++cc) {
            float a[8], bb[4];
            *(float4*)&a[0] = *(const float4*)&At[cc][ty * 4];
            *(float4*)&a[4] = *(const float4*)&At[cc][32 + ty * 4];
            *(float4*)&bb[0] = *(const float4*)&Bt[cc][tx * 4];
#pragma unroll
            for (int i = 0; i < 8; ++i)
#pragma unroll
                for (int j = 0; j < 4; ++j) acc[i][j] += a[i] * bb[j];
        }
        __syncthreads();
    }

#pragma unroll
    for (int i = 0; i < 8; ++i) {
        const int o = oBase + (i >> 2) * 32 + ty * 4 + (i & 3);
        const float inv = 1.0f / sqrtf(var[o] + 1e-5f);
        const float g = gamma[o] * inv;
        const float mn = mean[o], bt = beta[o];
        float4 st;
        st.x = (acc[i][0] - mn) * g + bt;
        st.y = (acc[i][1] - mn) * g + bt;
        st.z = (acc[i][2] - mn) * g + bt;
        st.w = (acc[i][3] - mn) * g + bt;
        *(float4*)&out[((size_t)b * O3_ + o) * TN_ + lBase + tx * 4] = st;
    }
}

// ---------------------------------------------------------------------------
// K2: LIF over t on qkv_bn, pack 32 head-dims into one uint32 spike word.
// ---------------------------------------------------------------------------
__global__ __launch_bounds__(256) void k2_lif_pack(
    const float* __restrict__ qkv,
    uint32_t* __restrict__ qb, uint32_t* __restrict__ kb, uint32_t* __restrict__ vb)
{
    const int n = threadIdx.x;
    const int g = blockIdx.x;
    const int b = blockIdx.y;
    const int which = g >> 3, h = g & 7;
    uint32_t* dst = (which == 0) ? qb : (which == 1) ? kb : vb;
    const float* src = qkv + ((size_t)b * O3_ + g * 32) * TN_;

    float memv[32];
#pragma unroll
    for (int d = 0; d < 32; ++d) memv[d] = 0.0f;
    uint32_t prev = 0;

    for (int t = 0; t < T_; ++t) {
        uint32_t bits = 0;
#pragma unroll
        for (int d = 0; d < 32; ++d) {
            const float xv = src[(size_t)d * TN_ + t * N_ + n];
            const float m = (memv[d] - 0.5f * (float)((prev >> d) & 1u)) * 0.25f + xv;
            memv[d] = m;
            const float s = quant1f(m);
            bits |= ((uint32_t)s) << d;
        }
        prev = bits;
        dst[((size_t)b * NH_ + h) * TN_ + t * N_ + n] = bits;
    }
}

// ---------------------------------------------------------------------------
// K3tg: fused ballot bit-transpose + cumulative Gram matrix, one block per bh.
// Masks stay in LDS; only Gf goes to global.
// ---------------------------------------------------------------------------
__global__ __launch_bounds__(256) void k3_tg(
    const uint32_t* __restrict__ kb, const uint32_t* __restrict__ vb,
    float* __restrict__ Gf)
{
    __shared__ uint64_t ks[4][32][4];  // [t][d][q]
    __shared__ uint64_t vs[4][32][4];
    const int bh = blockIdx.x;
    const int tid = threadIdx.x;
    const int q = tid >> 6, lane = tid & 63;

#pragma unroll
    for (int t = 0; t < T_; ++t) {
        const int j = t * N_ + q * 64 + lane;
        const uint32_t kw = kb[(size_t)bh * TN_ + j];
        const uint32_t vw = vb[(size_t)bh * TN_ + j];
#pragma unroll
        for (int d = 0; d < 32; ++d) {
            const uint64_t mk = __ballot((kw >> d) & 1u);
            const uint64_t mv = __ballot((vw >> d) & 1u);
            if (lane == 0) { ks[t][d][q] = mk; vs[t][d][q] = mv; }
        }
    }
    __syncthreads();

    const int d = tid & 31;
#pragma unroll
    for (int s = 0; s < 4; ++s) {
        const int d2 = (tid >> 5) + 8 * s;
        int cum = 0;
#pragma unroll
        for (int t = 0; t < T_; ++t) {
            int p = 0;
#pragma unroll
            for (int w = 0; w < 4; ++w) p += __popcll(ks[t][d2][w] & vs[t][d][w]);
            cum += p;
            Gf[(size_t)(bh * 4 + t) * 1024 + d2 * 32 + d] = (float)cum;
        }
    }
}

// ---------------------------------------------------------------------------
// K3s1: S1[i,d] = sum_{d2} qbit[i,d2] * G_ti[d2,d] -> oatt (unscaled)
// G column in 32 registers; no LDS in inner loop. 1024 blocks.
// ---------------------------------------------------------------------------
__global__ __launch_bounds__(256) void k3_s1(
    const uint32_t* __restrict__ qb, const float* __restrict__ Gf,
    float* __restrict__ oatt)
{
    const int grp = blockIdx.x;          // 0..15
    const int ti = grp >> 2, seg = grp & 3;
    const int h = blockIdx.y;
    const int b = blockIdx.z;
    const int bh = b * NH_ + h;
    const int tid = threadIdx.x;
    const int d = tid & 31;
    const int ig = tid >> 5;             // 0..7: 8 i's each

    const float* gsrc = Gf + (size_t)(bh * 4 + ti) * 1024 + d;
    float g[32];
#pragma unroll
    for (int d2 = 0; d2 < 32; ++d2) g[d2] = gsrc[d2 * 32];

    const uint32_t* qbh = qb + (size_t)bh * TN_;
    const int i0 = ti * N_ + seg * 64 + ig * 8;
#pragma unroll
    for (int s = 0; s < 8; ++s) {
        const int i = i0 + s;
        const uint32_t q = qbh[i];
        float acc = 0.0f;
#pragma unroll
        for (int d2 = 0; d2 < 32; ++d2)
            acc += ((q >> d2) & 1u) ? g[d2] : 0.0f;
        oatt[((size_t)b * TN_ + i) * C_ + h * 32 + d] = acc;
    }
}

// ---------------------------------------------------------------------------
// K3gemm: balanced split-K bias GEMM; bias window gathered straight from
// bias_table (strided x8, L2-resident). 640 blocks, K=256 each.
// ---------------------------------------------------------------------------
__global__ __launch_bounds__(256) void k3_bias_gemm(
    const uint32_t* __restrict__ vb, const float* __restrict__ bias_table,
    float* __restrict__ p0, float* __restrict__ p1,
    float* __restrict__ p2, float* __restrict__ p3)
{
    __shared__ float sbl[640];
    __shared__ float At[16][68];   // [j-in-chunk][i-local]
    __shared__ float Bt[16][132];  // [j-in-chunk][n-local]

    const int z = blockIdx.z;            // 0..79
    const int h = z / 10;
    const int p = z % 10;
    const int ti = TI_OF[p], tj = TJ_OF[p];
    const int dt = ti - tj;
    const int iT = blockIdx.y;           // 0..3
    const int nBase = blockIdx.x * 128;  // 0 or 128
    const int tid = threadIdx.x;

    // stage bias window directly from bias_table (head column h)
    const int base = 3363 + 961 * dt + 124 * iT - 480;
    for (int s = tid; s < 640; s += 256) {
        const int gidx = base + s;
        sbl[s] = (gidx < BIAS_ROWS_) ? bias_table[(size_t)gidx * NH_ + h] : 0.0f;
    }

    const int ty = tid >> 4, tx = tid & 15;

    // A-staging: thread (ccS = tx, iBase4 = ty*4)
    const int ccS = tx;
    const int iBase4 = ty * 4;
    const int sIdxBase = 31 * (iBase4 >> 4) + (iBase4 & 15) + 480 - ccS;

    // B-staging: thread (kkS = ty, n8 = tx*8)
    const int kkS = ty;
    const int n8 = tx * 8;
    const int nS = nBase + n8;
    const int bS = nS >> 5, d0S = nS & 31;
    const uint32_t* vbw = vb + ((size_t)bS * NH_ + h) * TN_ + tj * 256 + kkS;

    float acc[4][8];
#pragma unroll
    for (int i = 0; i < 4; ++i)
#pragma unroll
        for (int j = 0; j < 8; ++j) acc[i][j] = 0.0f;

    __syncthreads();  // sbl ready

    for (int kc = 0; kc < 16; ++kc) {
        {
            const int s0 = sIdxBase - 31 * kc;
            float4 av;
            av.x = sbl[s0];
            av.y = sbl[s0 + 1];
            av.z = sbl[s0 + 2];
            av.w = sbl[s0 + 3];
            *(float4*)&At[ccS][iBase4] = av;
        }
        {
            const uint32_t wd = vbw[kc * 16];
            float4 b0, b1;
            b0.x = (float)((wd >> d0S) & 1u);
            b0.y = (float)((wd >> (d0S + 1)) & 1u);
            b0.z = (float)((wd >> (d0S + 2)) & 1u);
            b0.w = (float)((wd >> (d0S + 3)) & 1u);
            b1.x = (float)((wd >> (d0S + 4)) & 1u);
            b1.y = (float)((wd >> (d0S + 5)) & 1u);
            b1.z = (float)((wd >> (d0S + 6)) & 1u);
            b1.w = (float)((wd >> (d0S + 7)) & 1u);
            *(float4*)&Bt[kkS][n8] = b0;
            *(float4*)&Bt[kkS][n8 + 4] = b1;
        }
        __syncthreads();
#pragma unroll
        for (int cc = 0; cc < 16; ++cc) {
            float a[4], bb[8];
            *(float4*)&a[0] = *(const float4*)&At[cc][ty * 4];
            *(float4*)&bb[0] = *(const float4*)&Bt[cc][tx * 8];
            *(float4*)&bb[4] = *(const float4*)&Bt[cc][tx * 8 + 4];
#pragma unroll
            for (int i = 0; i < 4; ++i)
#pragma unroll
                for (int j = 0; j < 8; ++j) acc[i][j] += a[i] * bb[j];
        }
        __syncthreads();
    }

    float* plane = (tj == 0) ? p0 : (tj == 1) ? p1 : (tj == 2) ? p2 : p3;
    const int nrows = (4 - tj) * 256;
    const int c0 = h * 32 + d0S;
#pragma unroll
    for (int r = 0; r < 4; ++r) {
        const int rowL = dt * 256 + iT * 64 + ty * 4 + r;
        float* dst = &plane[((size_t)bS * nrows + rowL) * 256 + c0];
        float4 s0, s1;
        s0.x = acc[r][0]; s0.y = acc[r][1]; s0.z = acc[r][2]; s0.w = acc[r][3];
        s1.x = acc[r][4]; s1.y = acc[r][5]; s1.z = acc[r][6]; s1.w = acc[r][7];
        *(float4*)&dst[0] = s0;
        *(float4*)&dst[4] = s1;
    }
}

// ---------------------------------------------------------------------------
// K4: combine S1 + bias partials, scale 0.125, LIF over t -> bit-packed spikes
// ---------------------------------------------------------------------------
__global__ __launch_bounds__(256) void k4_lif2(
    const float* __restrict__ oatt,
    const float* __restrict__ p0, const float* __restrict__ p1,
    const float* __restrict__ p2, const float* __restrict__ p3,
    uint32_t* __restrict__ s2c)
{
    const int c = threadIdx.x;
    const int n = blockIdx.x;
    const int b = blockIdx.y;
    const int lane = c & 63;
    float memv = 0.0f, spk = 0.0f;
    for (int t = 0; t < T_; ++t) {
        const int l = t * N_ + n;
        float v = oatt[((size_t)b * TN_ + l) * C_ + c];
        v += p0[((size_t)b * 1024 + l) * 256 + c];
        if (t >= 1) v += p1[((size_t)b * 768 + (l - 256)) * 256 + c];
        if (t >= 2) v += p2[((size_t)b * 512 + (l - 512)) * 256 + c];
        if (t >= 3) v += p3[((size_t)b * 256 + (l - 768)) * 256 + c];
        const float m = (memv - 0.5f * spk) * 0.25f + 0.125f * v;
        memv = m;
        const float s = quant1f(m);
        spk = s;
        const uint64_t mask = __ballot(s != 0.0f);
        if (lane == 0)
            s2c[((size_t)b * TN_ + l) * 8 + (c >> 5)] = (uint32_t)mask;
        else if (lane == 32)
            s2c[((size_t)b * TN_ + l) * 8 + (c >> 5)] = (uint32_t)(mask >> 32);
    }
}

// ---------------------------------------------------------------------------
// K5: proj GEMM + bias + BN, B operand expanded from bit-packed spikes.
// ---------------------------------------------------------------------------
__global__ __launch_bounds__(256) void k5_proj_gemm(
    const uint32_t* __restrict__ s2c, const float* __restrict__ w,
    const float* __restrict__ bp,
    const float* __restrict__ gamma, const float* __restrict__ beta,
    const float* __restrict__ mean, const float* __restrict__ var,
    float* __restrict__ pbn)
{
    __shared__ float At[16][36];
    __shared__ float Bt[16][132];
    const int b = blockIdx.z;
    const int oBase = blockIdx.y * 32;
    const int lBase = blockIdx.x * 128;
    const int tid = threadIdx.x;
    const int tx = tid & 31;
    const int ty = tid >> 5;

    const int a_row = tid >> 3, a_k2 = (tid & 7) * 2;
    const int b_ll = tid >> 1, b_sub = tid & 1;
    const uint32_t* srow = s2c + ((size_t)b * TN_ + lBase + b_ll) * 8;

    float acc[4][4];
#pragma unroll
    for (int i = 0; i < 4; ++i)
#pragma unroll
        for (int j = 0; j < 4; ++j) acc[i][j] = 0.0f;

    for (int kc = 0; kc < 16; ++kc) {
        const int k0 = kc * 16;
        {
            const float2 v = *(const float2*)&w[(size_t)(oBase + a_row) * C_ + k0 + a_k2];
            At[a_k2][a_row] = v.x;
            At[a_k2 + 1][a_row] = v.y;
        }
        {
            const uint32_t wd = srow[kc >> 1];
            const int sh = ((kc & 1) << 4) + (b_sub << 3);
#pragma unroll
            for (int u = 0; u < 8; ++u)
                Bt[(b_sub << 3) + u][b_ll] = (float)((wd >> (sh + u)) & 1u);
        }
        __syncthreads();
#pragma unroll
        for (int cc = 0; cc < 16; ++cc) {
            float a[4], bb[4];
            *(float4*)&a[0] = *(const float4*)&At[cc][ty * 4];
            *(float4*)&bb[0] = *(const float4*)&Bt[cc][tx * 4];
#pragma unroll
            for (int i = 0; i < 4; ++i)
#pragma unroll
                for (int j = 0; j < 4; ++j) acc[i][j] += a[i] * bb[j];
        }
        __syncthreads();
    }

#pragma unroll
    for (int i = 0; i < 4; ++i) {
        const int o = oBase + ty * 4 + i;
        const float inv = 1.0f / sqrtf(var[o] + 1e-5f);
        const float g = gamma[o] * inv;
        const float mn = mean[o], bt = beta[o], bpo = bp[o];
        float4 st;
        st.x = ((acc[i][0] + bpo) - mn) * g + bt;
        st.y = ((acc[i][1] + bpo) - mn) * g + bt;
        st.z = ((acc[i][2] + bpo) - mn) * g + bt;
        st.w = ((acc[i][3] + bpo) - mn) * g + bt;
        *(float4*)&pbn[((size_t)b * C_ + o) * TN_ + lBase + tx * 4] = st;
    }
}

// ---------------------------------------------------------------------------
// K6: final LIF over t, write output [T][B][C][N]
// ---------------------------------------------------------------------------
__global__ __launch_bounds__(256) void k6_lif3(
    const float* __restrict__ pbn, float* __restrict__ out)
{
    const int n = threadIdx.x;
    const int c = blockIdx.x;
    const int b = blockIdx.y;
    const float* src = pbn + ((size_t)b * C_ + c) * TN_;
    float memv = 0.0f, spk = 0.0f;
    for (int t = 0; t < T_; ++t) {
        const float m = (memv - 0.5f * spk) * 0.25f + src[t * N_ + n];
        memv = m;
        const float s = quant1f(m);
        out[(((size_t)t * B_ + b) * C_ + c) * N_ + n] = s;
        spk = s;
    }
}

// ---------------------------------------------------------------------------
extern "C" void kernel_launch(void* const* d_in, const int* in_sizes, int n_in,
                              void* d_out, int out_size, void* d_ws, size_t ws_size,
                              hipStream_t stream)
{
    const float* x          = (const float*)d_in[0];
    const float* w_qkv      = (const float*)d_in[1];
    const float* qkv_gamma  = (const float*)d_in[2];
    const float* qkv_beta   = (const float*)d_in[3];
    const float* qkv_mean   = (const float*)d_in[4];
    const float* qkv_var    = (const float*)d_in[5];
    const float* bias_table = (const float*)d_in[6];
    const float* w_proj     = (const float*)d_in[7];
    const float* b_proj     = (const float*)d_in[8];
    const float* proj_gamma = (const float*)d_in[9];
    const float* proj_beta  = (const float*)d_in[10];
    const float* proj_mean  = (const float*)d_in[11];
    const float* proj_var   = (const float*)d_in[12];
    float* out = (float*)d_out;

    // workspace layout (bytes)
    char* ws = (char*)d_ws;
    float*    qkv_bn = (float*)(ws + 0);            // 25165824 B (dead after K2)
    float*    Gf     = (float*)(ws + 524288);       //   262144 B (after K2)
    float*    part0  = (float*)(ws + 1048576);      //  8388608 B
    float*    part1  = (float*)(ws + 9437184);      //  6291456 B
    float*    part2  = (float*)(ws + 15728640);     //  4194304 B
    float*    part3  = (float*)(ws + 19922944);     //  2097152 B
    float*    oatt   = (float*)(ws + 25165824);     //  8388608 B (S1, unscaled)
    uint32_t* s2c    = (uint32_t*)(ws + 33554432);  //   262144 B (packed spikes)
    float*    pbn    = (float*)(ws + 41943040);     //  8388608 B
    uint32_t* qbits  = (uint32_t*)(ws + 50331648);  //   262144 B
    uint32_t* kbits  = (uint32_t*)(ws + 50593792);
    uint32_t* vbits  = (uint32_t*)(ws + 50855936);  // end 51118080

    k1_qkv_gemm<<<dim3(8, 12, 8), 256, 0, stream>>>(
        x, w_qkv, qkv_gamma, qkv_beta, qkv_mean, qkv_var, qkv_bn);

    k2_lif_pack<<<dim3(24, 8), 256, 0, stream>>>(qkv_bn, qbits, kbits, vbits);

    k3_tg<<<dim3(64), 256, 0, stream>>>(kbits, vbits, Gf);

    k3_s1<<<dim3(16, 8, 8), 256, 0, stream>>>(qbits, Gf, oatt);

    k3_bias_gemm<<<dim3(2, 4, 80), 256, 0, stream>>>(
        vbits, bias_table, part0, part1, part2, part3);

    k4_lif2<<<dim3(256, 8), 256, 0, stream>>>(oatt, part0, part1, part2, part3, s2c);

    k5_proj_gemm<<<dim3(8, 8, 8), 256, 0, stream>>>(
        s2c, w_proj, b_proj, proj_gamma, proj_beta, proj_mean, proj_var, pbn);

    k6_lif3<<<dim3(256, 8), 256, 0, stream>>>(pbn, out);
}